// Round 1
// baseline (96.432 us; speedup 1.0000x reference)
//
#include <hip/hip_runtime.h>
#include <math.h>

#define BB 64
#define ZZ 8
#define UU 8
#define PP 128
#define XX 64
#define HH 512

// ---------------------------------------------------------------------------
// Small GEMM + bias + optional ELU:  out[M,N] = act(A[M,K] @ W[K,N] + bias[N])
// One block per row (blockIdx.y), columns spread over blockIdx.x * blockDim.x.
// A-row staged in LDS; W reads are coalesced (consecutive cols per lane).
// 4 independent accumulators break the FMA dependency chain.
// ---------------------------------------------------------------------------
__global__ void mlp_layer(const float* __restrict__ A, const float* __restrict__ W,
                          const float* __restrict__ bias, float* __restrict__ out,
                          int K, int N, int do_elu) {
    __shared__ float As[HH];
    const int row = blockIdx.y;
    for (int k = threadIdx.x; k < K; k += blockDim.x) As[k] = A[row * K + k];
    __syncthreads();
    const int col = blockIdx.x * blockDim.x + threadIdx.x;
    if (col >= N) return;
    float a0 = 0.f, a1 = 0.f, a2 = 0.f, a3 = 0.f;
    for (int k = 0; k < K; k += 4) {           // K is always a multiple of 4 here
        a0 = fmaf(As[k + 0], W[(k + 0) * N + col], a0);
        a1 = fmaf(As[k + 1], W[(k + 1) * N + col], a1);
        a2 = fmaf(As[k + 2], W[(k + 2) * N + col], a2);
        a3 = fmaf(As[k + 3], W[(k + 3) * N + col], a3);
    }
    float acc = (a0 + a1) + (a2 + a3) + bias[col];
    if (do_elu) acc = acc > 0.f ? acc : (expf(acc) - 1.f);
    out[row * N + col] = acc;
}

// ---------------------------------------------------------------------------
// Per-(b,z,u) bilinear forms over Linv (128x128 fp32 each):
//   mu  = sum_{i,j} phi_b[i] * L[i,j] * Qv[j]
//   cov = exp(logSigEps[u]) * (1 + sum_{i,j} phi_b[i] * L[i,j] * phi_b[j])
// One block (256 threads) per matrix; 16 float4 loads/thread, fully coalesced.
// ---------------------------------------------------------------------------
__global__ __launch_bounds__(256) void bilinear_kernel(
    const float* __restrict__ Linv, const float* __restrict__ Q,
    const float* __restrict__ phi, const float* __restrict__ logSigEps,
    float* __restrict__ out_mu, float* __restrict__ out_cov) {
    __shared__ __align__(16) float Ps[PP];
    __shared__ __align__(16) float Qs[PP];
    __shared__ float red[8];

    const int bzu = blockIdx.x;        // b*64 + z*8 + u
    const int b   = bzu >> 6;          // / (Z*U)
    const int u   = bzu & 7;           // % U
    const int tid = threadIdx.x;

    if (tid < PP) {
        Ps[tid] = phi[b * PP + tid];
        Qs[tid] = Q[bzu * PP + tid];   // Q[b,z,u,0,:]
    }
    __syncthreads();

    const float4* L4 = (const float4*)(Linv + (size_t)bzu * (PP * PP));
    float accM = 0.f, accS = 0.f;
    #pragma unroll
    for (int it = 0; it < 16; ++it) {
        const int f  = it * 256 + tid;         // float4 index within the matrix
        const float4 L = L4[f];
        const int i  = f >> 5;                 // row: (4f)/128
        const int j0 = (f & 31) << 2;          // col start: (4f)%128
        const float4 q = *(const float4*)(Qs + j0);
        const float4 p = *(const float4*)(Ps + j0);
        const float pi = Ps[i];                // uniform per half-wave -> broadcast
        const float sm = L.x * q.x + L.y * q.y + L.z * q.z + L.w * q.w;
        const float sp = L.x * p.x + L.y * p.y + L.z * p.z + L.w * p.w;
        accM = fmaf(pi, sm, accM);
        accS = fmaf(pi, sp, accS);
    }

    // 64-lane butterfly reduce
    for (int off = 32; off; off >>= 1) {
        accM += __shfl_down(accM, off, 64);
        accS += __shfl_down(accS, off, 64);
    }
    const int wid = tid >> 6;
    if ((tid & 63) == 0) { red[wid] = accM; red[4 + wid] = accS; }
    __syncthreads();
    if (tid == 0) {
        const float m = (red[0] + red[1]) + (red[2] + red[3]);
        const float s = (red[4] + red[5]) + (red[6] + red[7]);
        out_mu[bzu]  = m;
        out_cov[bzu] = expf(logSigEps[u]) * (1.f + s);
    }
}

extern "C" void kernel_launch(void* const* d_in, const int* in_sizes, int n_in,
                              void* d_out, int out_size, void* d_ws, size_t ws_size,
                              hipStream_t stream) {
    const float* x         = (const float*)d_in[0];
    const float* Linv      = (const float*)d_in[1];
    const float* Q         = (const float*)d_in[2];
    const float* W1        = (const float*)d_in[3];
    const float* b1        = (const float*)d_in[4];
    const float* W2        = (const float*)d_in[5];
    const float* b2        = (const float*)d_in[6];
    const float* W3        = (const float*)d_in[7];
    const float* b3        = (const float*)d_in[8];
    const float* W4        = (const float*)d_in[9];
    const float* b4        = (const float*)d_in[10];
    const float* logSigEps = (const float*)d_in[11];

    float* ws  = (float*)d_ws;
    float* h1  = ws;                 // 64*512
    float* h2  = ws + BB * HH;       // 64*512
    float* phi = ws + 2 * BB * HH;   // 64*128

    // MLP: x -> h1 -> h2 -> h1 (reuse) -> phi
    mlp_layer<<<dim3(2, BB), 256, 0, stream>>>(x,  W1, b1, h1, XX, HH, 1);
    mlp_layer<<<dim3(2, BB), 256, 0, stream>>>(h1, W2, b2, h2, HH, HH, 1);
    mlp_layer<<<dim3(2, BB), 256, 0, stream>>>(h2, W3, b3, h1, HH, HH, 1);
    mlp_layer<<<dim3(1, BB), 128, 0, stream>>>(h1, W4, b4, phi, HH, PP, 0);

    float* out_mu  = (float*)d_out;          // (B,Z,U,1) = 4096 floats
    float* out_cov = out_mu + BB * ZZ * UU;  // (B,Z,U)   = 4096 floats

    bilinear_kernel<<<BB * ZZ * UU, 256, 0, stream>>>(Linv, Q, phi, logSigEps,
                                                      out_mu, out_cov);
}

// Round 3
// 86.911 us; speedup vs baseline: 1.1095x; 1.1095x over previous
//
#include <hip/hip_runtime.h>
#include <math.h>

#define BB 64
#define ZZ 8
#define UU 8
#define PP 128
#define XX 64
#define HH 512

typedef float f32x4 __attribute__((ext_vector_type(4)));
typedef float f32x2 __attribute__((ext_vector_type(2)));

__device__ __forceinline__ float elu(float v) {
    return v > 0.f ? v : (expf(v) - 1.f);
}

// ---------------------------------------------------------------------------
// Fused 4-layer MLP. One block per batch row (64 blocks, 256 threads).
// Activations live in LDS; weights streamed with float2 loads (coalesced,
// 512 B/wave/instruction). 4-way K-unroll for ILP.
//   h1 = elu(x @ W1 + b1); h2 = elu(h1 @ W2 + b2); h3 = elu(h2 @ W3 + b3);
//   phi = h3 @ W4 + b4
// ---------------------------------------------------------------------------
__global__ __launch_bounds__(256) void mlp_fused(
    const float* __restrict__ x,
    const float* __restrict__ W1, const float* __restrict__ b1,
    const float* __restrict__ W2, const float* __restrict__ b2,
    const float* __restrict__ W3, const float* __restrict__ b3,
    const float* __restrict__ W4, const float* __restrict__ b4,
    float* __restrict__ phi) {
    __shared__ float xs[XX];
    __shared__ float hA[HH];
    __shared__ float hB[HH];

    const int b   = blockIdx.x;
    const int tid = threadIdx.x;

    if (tid < XX) xs[tid] = x[b * XX + tid];
    __syncthreads();

    // ---- layer 1: [64] @ [64,512] -> hA ----
    {
        const f32x2* W = (const f32x2*)W1;       // [XX][HH/2]
        f32x2 a0 = {0.f, 0.f}, a1 = {0.f, 0.f};
        #pragma unroll 8
        for (int k = 0; k < XX; k += 2) {
            const f32x2 w0 = W[(k + 0) * (HH / 2) + tid];
            const f32x2 w1 = W[(k + 1) * (HH / 2) + tid];
            const float s0 = xs[k + 0], s1 = xs[k + 1];
            a0.x = fmaf(s0, w0.x, a0.x); a0.y = fmaf(s0, w0.y, a0.y);
            a1.x = fmaf(s1, w1.x, a1.x); a1.y = fmaf(s1, w1.y, a1.y);
        }
        const f32x2 bb = ((const f32x2*)b1)[tid];
        hA[2 * tid + 0] = elu(a0.x + a1.x + bb.x);
        hA[2 * tid + 1] = elu(a0.y + a1.y + bb.y);
    }
    __syncthreads();

    // ---- layer 2: hA @ [512,512] -> hB ----
    {
        const f32x2* W = (const f32x2*)W2;       // [HH][HH/2]
        f32x2 a0 = {0.f, 0.f}, a1 = {0.f, 0.f}, a2 = {0.f, 0.f}, a3 = {0.f, 0.f};
        #pragma unroll 8
        for (int k = 0; k < HH; k += 4) {
            const f32x2 w0 = W[(k + 0) * (HH / 2) + tid];
            const f32x2 w1 = W[(k + 1) * (HH / 2) + tid];
            const f32x2 w2 = W[(k + 2) * (HH / 2) + tid];
            const f32x2 w3 = W[(k + 3) * (HH / 2) + tid];
            const float s0 = hA[k + 0], s1 = hA[k + 1], s2 = hA[k + 2], s3 = hA[k + 3];
            a0.x = fmaf(s0, w0.x, a0.x); a0.y = fmaf(s0, w0.y, a0.y);
            a1.x = fmaf(s1, w1.x, a1.x); a1.y = fmaf(s1, w1.y, a1.y);
            a2.x = fmaf(s2, w2.x, a2.x); a2.y = fmaf(s2, w2.y, a2.y);
            a3.x = fmaf(s3, w3.x, a3.x); a3.y = fmaf(s3, w3.y, a3.y);
        }
        const f32x2 bb = ((const f32x2*)b2)[tid];
        hB[2 * tid + 0] = elu((a0.x + a1.x) + (a2.x + a3.x) + bb.x);
        hB[2 * tid + 1] = elu((a0.y + a1.y) + (a2.y + a3.y) + bb.y);
    }
    __syncthreads();

    // ---- layer 3: hB @ [512,512] -> hA ----
    {
        const f32x2* W = (const f32x2*)W3;
        f32x2 a0 = {0.f, 0.f}, a1 = {0.f, 0.f}, a2 = {0.f, 0.f}, a3 = {0.f, 0.f};
        #pragma unroll 8
        for (int k = 0; k < HH; k += 4) {
            const f32x2 w0 = W[(k + 0) * (HH / 2) + tid];
            const f32x2 w1 = W[(k + 1) * (HH / 2) + tid];
            const f32x2 w2 = W[(k + 2) * (HH / 2) + tid];
            const f32x2 w3 = W[(k + 3) * (HH / 2) + tid];
            const float s0 = hB[k + 0], s1 = hB[k + 1], s2 = hB[k + 2], s3 = hB[k + 3];
            a0.x = fmaf(s0, w0.x, a0.x); a0.y = fmaf(s0, w0.y, a0.y);
            a1.x = fmaf(s1, w1.x, a1.x); a1.y = fmaf(s1, w1.y, a1.y);
            a2.x = fmaf(s2, w2.x, a2.x); a2.y = fmaf(s2, w2.y, a2.y);
            a3.x = fmaf(s3, w3.x, a3.x); a3.y = fmaf(s3, w3.y, a3.y);
        }
        const f32x2 bb = ((const f32x2*)b3)[tid];
        hA[2 * tid + 0] = elu((a0.x + a1.x) + (a2.x + a3.x) + bb.x);
        hA[2 * tid + 1] = elu((a0.y + a1.y) + (a2.y + a3.y) + bb.y);
    }
    __syncthreads();

    // ---- layer 4: hA @ [512,128] -> phi (no activation) ----
    if (tid < PP) {
        float a0 = 0.f, a1 = 0.f, a2 = 0.f, a3 = 0.f;
        #pragma unroll 8
        for (int k = 0; k < HH; k += 4) {
            a0 = fmaf(hA[k + 0], W4[(k + 0) * PP + tid], a0);
            a1 = fmaf(hA[k + 1], W4[(k + 1) * PP + tid], a1);
            a2 = fmaf(hA[k + 2], W4[(k + 2) * PP + tid], a2);
            a3 = fmaf(hA[k + 3], W4[(k + 3) * PP + tid], a3);
        }
        phi[b * PP + tid] = (a0 + a1) + (a2 + a3) + b4[tid];
    }
}

// ---------------------------------------------------------------------------
// Per-(b,z,u) bilinear forms over Linv (128x128 fp32 each):
//   mu  = sum_{i,j} phi_b[i] * L[i,j] * Qv[j]
//   cov = exp(logSigEps[u]) * (1 + sum_{i,j} phi_b[i] * L[i,j] * phi_b[j])
// One block (256 threads) per matrix; 16 nontemporal float4 loads/thread.
// ---------------------------------------------------------------------------
__global__ __launch_bounds__(256) void bilinear_kernel(
    const float* __restrict__ Linv, const float* __restrict__ Q,
    const float* __restrict__ phi, const float* __restrict__ logSigEps,
    float* __restrict__ out_mu, float* __restrict__ out_cov) {
    __shared__ __align__(16) float Ps[PP];
    __shared__ __align__(16) float Qs[PP];
    __shared__ float red[8];

    const int bzu = blockIdx.x;        // b*64 + z*8 + u
    const int b   = bzu >> 6;
    const int u   = bzu & 7;
    const int tid = threadIdx.x;

    if (tid < PP) {
        Ps[tid] = phi[b * PP + tid];
        Qs[tid] = Q[bzu * PP + tid];   // Q[b,z,u,0,:]
    }
    __syncthreads();

    const f32x4* L4 = (const f32x4*)(Linv + (size_t)bzu * (PP * PP));
    float accM = 0.f, accS = 0.f;
    #pragma unroll
    for (int it = 0; it < 16; ++it) {
        const int f  = it * 256 + tid;         // float4 index within the matrix
        const f32x4 L = __builtin_nontemporal_load(L4 + f);
        const int i  = f >> 5;                 // row: (4f)/128
        const int j0 = (f & 31) << 2;          // col start: (4f)%128
        const f32x4 q = *(const f32x4*)(Qs + j0);
        const f32x4 p = *(const f32x4*)(Ps + j0);
        const float pi = Ps[i];
        const float sm = L.x * q.x + L.y * q.y + L.z * q.z + L.w * q.w;
        const float sp = L.x * p.x + L.y * p.y + L.z * p.z + L.w * p.w;
        accM = fmaf(pi, sm, accM);
        accS = fmaf(pi, sp, accS);
    }

    for (int off = 32; off; off >>= 1) {
        accM += __shfl_down(accM, off, 64);
        accS += __shfl_down(accS, off, 64);
    }
    const int wid = tid >> 6;
    if ((tid & 63) == 0) { red[wid] = accM; red[4 + wid] = accS; }
    __syncthreads();
    if (tid == 0) {
        const float m = (red[0] + red[1]) + (red[2] + red[3]);
        const float s = (red[4] + red[5]) + (red[6] + red[7]);
        out_mu[bzu]  = m;
        out_cov[bzu] = expf(logSigEps[u]) * (1.f + s);
    }
}

extern "C" void kernel_launch(void* const* d_in, const int* in_sizes, int n_in,
                              void* d_out, int out_size, void* d_ws, size_t ws_size,
                              hipStream_t stream) {
    const float* x         = (const float*)d_in[0];
    const float* Linv      = (const float*)d_in[1];
    const float* Q         = (const float*)d_in[2];
    const float* W1        = (const float*)d_in[3];
    const float* b1        = (const float*)d_in[4];
    const float* W2        = (const float*)d_in[5];
    const float* b2        = (const float*)d_in[6];
    const float* W3        = (const float*)d_in[7];
    const float* b3        = (const float*)d_in[8];
    const float* W4        = (const float*)d_in[9];
    const float* b4        = (const float*)d_in[10];
    const float* logSigEps = (const float*)d_in[11];

    float* phi = (float*)d_ws;               // 64*128 floats

    mlp_fused<<<BB, 256, 0, stream>>>(x, W1, b1, W2, b2, W3, b3, W4, b4, phi);

    float* out_mu  = (float*)d_out;          // (B,Z,U,1) = 4096 floats
    float* out_cov = out_mu + BB * ZZ * UU;  // (B,Z,U)   = 4096 floats

    bilinear_kernel<<<BB * ZZ * UU, 256, 0, stream>>>(Linv, Q, phi, logSigEps,
                                                      out_mu, out_cov);
}

// Round 4
// 69.185 us; speedup vs baseline: 1.3938x; 1.2562x over previous
//
#include <hip/hip_runtime.h>
#include <math.h>

#define BB 64
#define ZZ 8
#define UU 8
#define PP 128
#define XX 64
#define HH 512

typedef float f32x4 __attribute__((ext_vector_type(4)));

__device__ __forceinline__ float elu(float v) {
    return v > 0.f ? v : (expf(v) - 1.f);
}

// ---------------------------------------------------------------------------
// One MLP layer, column-split across blocks so weight bytes per block stay
// small (the per-CU L2 fabric ~56 B/cyc is the wall for fat per-row blocks).
//   grid = (N/128, 64 rows), 256 threads.
//   thread: g = tid&31 -> f32x4 column group, ks = tid>>5 -> 8-way K slice.
// Per block: weight slice K x 128 x 4B (256 KB for K=512) -> ~2 us fabric.
// Partial sums reduced through LDS; 32 threads apply bias/ELU and store.
// ---------------------------------------------------------------------------
template<int K, bool ELU>
__global__ __launch_bounds__(256) void layer_kernel(
    const float* __restrict__ in, const float* __restrict__ W,
    const float* __restrict__ bias, float* __restrict__ out, int N) {
    __shared__ __align__(16) float xs[K];
    __shared__ f32x4 red[8][32];

    const int r   = blockIdx.y;
    const int c0  = blockIdx.x * 128;
    const int tid = threadIdx.x;

    if (tid < K / 4) ((f32x4*)xs)[tid] = ((const f32x4*)(in + (size_t)r * K))[tid];
    __syncthreads();

    const int g    = tid & 31;
    const int ks   = tid >> 5;
    const int kBeg = ks * (K / 8);
    const float* Wp = W + (size_t)kBeg * N + c0 + g * 4;

    f32x4 acc = {0.f, 0.f, 0.f, 0.f};
    #pragma unroll 8
    for (int k = 0; k < K / 8; ++k) {
        const f32x4 w = *(const f32x4*)(Wp + (size_t)k * N);
        const float s = xs[kBeg + k];
        acc.x = fmaf(s, w.x, acc.x);
        acc.y = fmaf(s, w.y, acc.y);
        acc.z = fmaf(s, w.z, acc.z);
        acc.w = fmaf(s, w.w, acc.w);
    }
    red[ks][g] = acc;
    __syncthreads();

    if (tid < 32) {
        f32x4 a = red[0][tid];
        #pragma unroll
        for (int s = 1; s < 8; ++s) {
            const f32x4 b = red[s][tid];
            a.x += b.x; a.y += b.y; a.z += b.z; a.w += b.w;
        }
        const f32x4 bb = *(const f32x4*)(bias + c0 + tid * 4);
        a.x += bb.x; a.y += bb.y; a.z += bb.z; a.w += bb.w;
        if (ELU) { a.x = elu(a.x); a.y = elu(a.y); a.z = elu(a.z); a.w = elu(a.w); }
        *(f32x4*)(out + (size_t)r * N + c0 + tid * 4) = a;
    }
}

// ---------------------------------------------------------------------------
// Per-(b,z,u) bilinear forms over Linv (128x128 fp32 each):
//   mu  = sum_{i,j} phi_b[i] * L[i,j] * Qv[j]
//   cov = exp(logSigEps[u]) * (1 + sum_{i,j} phi_b[i] * L[i,j] * phi_b[j])
// One block (256 threads) per matrix; 16 f32x4 loads/thread, coalesced.
// KEY: j0 = (f&31)<<2 is iteration-invariant (256 == 0 mod 32), so the q/p
// fragments are hoisted to registers -- inner loop has zero b128 LDS reads.
// ---------------------------------------------------------------------------
__global__ __launch_bounds__(256) void bilinear_kernel(
    const float* __restrict__ Linv, const float* __restrict__ Q,
    const float* __restrict__ phi, const float* __restrict__ logSigEps,
    float* __restrict__ out_mu, float* __restrict__ out_cov) {
    __shared__ __align__(16) float Ps[PP];
    __shared__ __align__(16) float Qs[PP];
    __shared__ float red[8];

    const int bzu = blockIdx.x;        // b*64 + z*8 + u
    const int b   = bzu >> 6;
    const int u   = bzu & 7;
    const int tid = threadIdx.x;

    if (tid < 32)      ((f32x4*)Ps)[tid]      = ((const f32x4*)(phi + (size_t)b * PP))[tid];
    else if (tid < 64) ((f32x4*)Qs)[tid - 32] = ((const f32x4*)(Q + (size_t)bzu * PP))[tid - 32];
    __syncthreads();

    const int j0 = (tid & 31) << 2;            // constant across iterations
    const f32x4 q = *(const f32x4*)(Qs + j0);
    const f32x4 p = *(const f32x4*)(Ps + j0);

    const f32x4* L4 = (const f32x4*)(Linv + (size_t)bzu * (PP * PP));
    float accM = 0.f, accS = 0.f;
    #pragma unroll
    for (int it = 0; it < 16; ++it) {
        const int f = it * 256 + tid;          // float4 index within the matrix
        const f32x4 L = L4[f];
        const float pi = Ps[f >> 5];           // 2 addrs/wave -> LDS broadcast
        const float sm = L.x * q.x + L.y * q.y + L.z * q.z + L.w * q.w;
        const float sp = L.x * p.x + L.y * p.y + L.z * p.z + L.w * p.w;
        accM = fmaf(pi, sm, accM);
        accS = fmaf(pi, sp, accS);
    }

    for (int off = 32; off; off >>= 1) {
        accM += __shfl_down(accM, off, 64);
        accS += __shfl_down(accS, off, 64);
    }
    const int wid = tid >> 6;
    if ((tid & 63) == 0) { red[wid] = accM; red[4 + wid] = accS; }
    __syncthreads();
    if (tid == 0) {
        const float m = (red[0] + red[1]) + (red[2] + red[3]);
        const float s = (red[4] + red[5]) + (red[6] + red[7]);
        out_mu[bzu]  = m;
        out_cov[bzu] = expf(logSigEps[u]) * (1.f + s);
    }
}

extern "C" void kernel_launch(void* const* d_in, const int* in_sizes, int n_in,
                              void* d_out, int out_size, void* d_ws, size_t ws_size,
                              hipStream_t stream) {
    const float* x         = (const float*)d_in[0];
    const float* Linv      = (const float*)d_in[1];
    const float* Q         = (const float*)d_in[2];
    const float* W1        = (const float*)d_in[3];
    const float* b1        = (const float*)d_in[4];
    const float* W2        = (const float*)d_in[5];
    const float* b2        = (const float*)d_in[6];
    const float* W3        = (const float*)d_in[7];
    const float* b3        = (const float*)d_in[8];
    const float* W4        = (const float*)d_in[9];
    const float* b4        = (const float*)d_in[10];
    const float* logSigEps = (const float*)d_in[11];

    float* ws  = (float*)d_ws;
    float* h1  = ws;                 // 64*512
    float* h2  = ws + BB * HH;       // 64*512
    float* phi = ws + 2 * BB * HH;   // 64*128

    layer_kernel<XX, true ><<<dim3(4, BB), 256, 0, stream>>>(x,  W1, b1, h1,  HH);
    layer_kernel<HH, true ><<<dim3(4, BB), 256, 0, stream>>>(h1, W2, b2, h2,  HH);
    layer_kernel<HH, true ><<<dim3(4, BB), 256, 0, stream>>>(h2, W3, b3, h1,  HH);
    layer_kernel<HH, false><<<dim3(1, BB), 256, 0, stream>>>(h1, W4, b4, phi, PP);

    float* out_mu  = (float*)d_out;          // (B,Z,U,1) = 4096 floats
    float* out_cov = out_mu + BB * ZZ * UU;  // (B,Z,U)   = 4096 floats

    bilinear_kernel<<<BB * ZZ * UU, 256, 0, stream>>>(Linv, Q, phi, logSigEps,
                                                      out_mu, out_cov);
}